// Round 3
// baseline (298.151 us; speedup 1.0000x reference)
//
#include <hip/hip_runtime.h>

#define N_NODES 50000
#define N_EDGES 800000
#define IN_C    128
#define HID_C   128
#define OUT_C   64

typedef unsigned int   uint32;
typedef unsigned short ushort16;

__device__ __forceinline__ ushort16 f2bf(float f) {
    uint32 u = __float_as_uint(f);
    u += 0x7FFFu + ((u >> 16) & 1u);        // RNE
    return (ushort16)(u >> 16);
}
__device__ __forceinline__ float bf_lo(uint32 h) { return __uint_as_float(h << 16); }
__device__ __forceinline__ float bf_hi(uint32 h) { return __uint_as_float(h & 0xFFFF0000u); }

__device__ __forceinline__ ushort16 f2h_bits(float f) {
    union { _Float16 h; ushort16 u; } cv;
    cv.h = (_Float16)f;
    return cv.u;
}
__device__ __forceinline__ float h_bits2f(uint32 bits) {
    union { ushort16 u; _Float16 h; } cv;
    cv.u = (ushort16)bits;
    return (float)cv.h;
}

// ---------------- GEMM: C[M,N](bf16) = A[M,128](fp32) * W[128,N](fp32) -------
template<int N, int RPT>
__global__ __launch_bounds__(256) void gemm_kernel(const float* __restrict__ A,
                                                   const float* __restrict__ W,
                                                   ushort16* __restrict__ C, int M) {
    constexpr int BK   = 16;
    constexpr int COLT = N / 4;
    constexpr int BM   = (256 / COLT) * RPT;       // 64
    __shared__ float As[BK][BM + 4];
    __shared__ float Ws[BK][N];

    const int tid      = threadIdx.x;
    const int colLane  = tid % COLT;
    const int rowGroup = tid / COLT;
    const int blockRow = blockIdx.x * BM;

    float acc[RPT][4];
#pragma unroll
    for (int i = 0; i < RPT; i++)
#pragma unroll
        for (int j = 0; j < 4; j++) acc[i][j] = 0.f;

    for (int kk = 0; kk < 128; kk += BK) {
        {
            int r  = tid / 4;
            int k4 = (tid % 4) * 4;
            int gr = blockRow + r; if (gr > M - 1) gr = M - 1;
            float4 v = *((const float4*)&A[gr * 128 + kk + k4]);
            As[k4 + 0][r] = v.x; As[k4 + 1][r] = v.y;
            As[k4 + 2][r] = v.z; As[k4 + 3][r] = v.w;
        }
#pragma unroll
        for (int p = 0; p < (BK * N) / 1024; p++) {
            int l4 = tid + 256 * p;
            int k  = l4 / (N / 4), c4 = l4 % (N / 4);
            float4 v = *((const float4*)&W[(kk + k) * N + c4 * 4]);
            *((float4*)&Ws[k][c4 * 4]) = v;
        }
        __syncthreads();

#pragma unroll
        for (int k = 0; k < BK; k++) {
            float4 w = *((const float4*)&Ws[k][colLane * 4]);
            float a[RPT];
#pragma unroll
            for (int i = 0; i < RPT; i += 4) {
                float4 av = *((const float4*)&As[k][rowGroup * RPT + i]);
                a[i] = av.x; a[i + 1] = av.y; a[i + 2] = av.z; a[i + 3] = av.w;
            }
#pragma unroll
            for (int i = 0; i < RPT; i++) {
                acc[i][0] += a[i] * w.x; acc[i][1] += a[i] * w.y;
                acc[i][2] += a[i] * w.z; acc[i][3] += a[i] * w.w;
            }
        }
        __syncthreads();
    }

#pragma unroll
    for (int i = 0; i < RPT; i++) {
        int r = blockRow + rowGroup * RPT + i;
        if (r < M) {
            ushort4 pk;
            pk.x = f2bf(acc[i][0]); pk.y = f2bf(acc[i][1]);
            pk.z = f2bf(acc[i][2]); pk.w = f2bf(acc[i][3]);
            *((ushort4*)&C[r * N + colLane * 4]) = pk;
        }
    }
}

// ---------------- CSR build --------------------------------------------------
__global__ void hist_kernel(const int* __restrict__ ei, int* __restrict__ counts) {
    int e = blockIdx.x * 256 + threadIdx.x;
    if (e < N_EDGES) atomicAdd(&counts[ei[N_EDGES + e]], 1);
}

__global__ void scan1_kernel(const int* __restrict__ counts, int* __restrict__ rowStart,
                             int* __restrict__ blockSums, int n) {
    __shared__ int lds[256];
    int t = threadIdx.x, g = blockIdx.x * 256 + t;
    int v = (g < n) ? counts[g] : 0;
    lds[t] = v; __syncthreads();
#pragma unroll
    for (int off = 1; off < 256; off <<= 1) {
        int a = (t >= off) ? lds[t - off] : 0;
        __syncthreads();
        lds[t] += a;
        __syncthreads();
    }
    if (g < n) rowStart[g] = lds[t] - v;
    if (t == 255) blockSums[blockIdx.x] = lds[255];
}

__global__ void scan2_kernel(int* __restrict__ blockSums, int nb) {
    __shared__ int lds[256];
    int t = threadIdx.x;
    int v = (t < nb) ? blockSums[t] : 0;
    lds[t] = v; __syncthreads();
#pragma unroll
    for (int off = 1; off < 256; off <<= 1) {
        int a = (t >= off) ? lds[t - off] : 0;
        __syncthreads();
        lds[t] += a;
        __syncthreads();
    }
    if (t < nb) blockSums[t] = lds[t] - v;
}

// finalize rowStart and also init cursor = rowStart
__global__ void scan3_kernel(int* __restrict__ rowStart, const int* __restrict__ blockSums,
                             int* __restrict__ cursor, int n) {
    int g = blockIdx.x * 256 + threadIdx.x;
    if (g < n) {
        int v = rowStart[g] + blockSums[blockIdx.x];
        rowStart[g] = v;
        cursor[g]   = v;
    }
    if (g == 0) rowStart[n] = N_EDGES;
}

// pack (src:u16 | f16(w)<<16) and scatter into CSR position via cursor atomic
__global__ void scatter_kernel(const int* __restrict__ ei, const float* __restrict__ ew,
                               int* __restrict__ cursor, uint32* __restrict__ pairs) {
    int e = blockIdx.x * 256 + threadIdx.x;
    if (e < N_EDGES) {
        int dst = ei[N_EDGES + e];
        uint32 pk = (uint32)(ei[e]) | ((uint32)f2h_bits(ew[e]) << 16);
        int pos = atomicAdd(&cursor[dst], 1);
        pairs[pos] = pk;
    }
}

// ---------------- Aggregations ----------------------------------------------
// layer 1: A1[i] = relu(b1 + sum_e w_e * H1[src_e]); H1 bf16x2 per lane (128 ch)
__global__ __launch_bounds__(256) void agg1_kernel(const uint32* __restrict__ H1,
                                                   const int* __restrict__ rowStart,
                                                   const uint32* __restrict__ pairs,
                                                   const float* __restrict__ b1,
                                                   float* __restrict__ A1) {
    int node = blockIdx.x * 4 + (threadIdx.x >> 6);
    int lane = threadIdx.x & 63;
    if (node >= N_NODES) return;
    int s = rowStart[node], e = rowStart[node + 1];
    float2 acc = ((const float2*)b1)[lane];
    int i = s;
    for (; i + 8 <= e; i += 8) {
        uint32 p[8], h[8];
#pragma unroll
        for (int j = 0; j < 8; j++) p[j] = pairs[i + j];
#pragma unroll
        for (int j = 0; j < 8; j++) h[j] = H1[(p[j] & 0xFFFFu) * 64 + lane];
#pragma unroll
        for (int j = 0; j < 8; j++) {
            float w = h_bits2f(p[j] >> 16);
            acc.x += w * bf_lo(h[j]);
            acc.y += w * bf_hi(h[j]);
        }
    }
    for (; i < e; i++) {
        uint32 p = pairs[i];
        uint32 h = H1[(p & 0xFFFFu) * 64 + lane];
        float  w = h_bits2f(p >> 16);
        acc.x += w * bf_lo(h);
        acc.y += w * bf_hi(h);
    }
    float2 r; r.x = fmaxf(acc.x, 0.f); r.y = fmaxf(acc.y, 0.f);
    ((float2*)A1)[node * 64 + lane] = r;
}

// layer 2: out[i] = b2 + sum_e H2[src_e]; H2 bf16 per lane (64 ch)
__global__ __launch_bounds__(256) void agg2_kernel(const ushort16* __restrict__ H2,
                                                   const int* __restrict__ rowStart,
                                                   const uint32* __restrict__ pairs,
                                                   const float* __restrict__ b2,
                                                   float* __restrict__ out) {
    int node = blockIdx.x * 4 + (threadIdx.x >> 6);
    int lane = threadIdx.x & 63;
    if (node >= N_NODES) return;
    int s = rowStart[node], e = rowStart[node + 1];
    float acc = b2[lane];
    int i = s;
    for (; i + 8 <= e; i += 8) {
        uint32 v[8];
#pragma unroll
        for (int j = 0; j < 8; j++) v[j] = H2[(pairs[i + j] & 0xFFFFu) * 64 + lane];
#pragma unroll
        for (int j = 0; j < 8; j++) acc += __uint_as_float(v[j] << 16);
    }
    for (; i < e; i++) {
        uint32 v = H2[(pairs[i] & 0xFFFFu) * 64 + lane];
        acc += __uint_as_float(v << 16);
    }
    out[node * 64 + lane] = acc;
}

// ---------------- launch -----------------------------------------------------
extern "C" void kernel_launch(void* const* d_in, const int* in_sizes, int n_in,
                              void* d_out, int out_size, void* d_ws, size_t ws_size,
                              hipStream_t stream) {
    const float* x  = (const float*)d_in[0];
    const int*   ei = (const int*)  d_in[1];   // [2, E] int32
    const float* ew = (const float*)d_in[2];
    const float* W1 = (const float*)d_in[3];
    const float* b1 = (const float*)d_in[4];
    const float* W2 = (const float*)d_in[5];
    const float* b2 = (const float*)d_in[6];
    float* out = (float*)d_out;

    // workspace layout
    float*    A1    = (float*)d_ws;                              // 50000*128 f32
    uint32*   H1    = (uint32*)(A1 + (size_t)N_NODES * HID_C);   // 50000*64 u32 (bf16x2)
    ushort16* H2    = (ushort16*)(H1 + (size_t)N_NODES * 64);    // 50000*64 bf16
    uint32*   pairs = (uint32*)(H2 + (size_t)N_NODES * OUT_C);   // 800000 (src u16 | f16 w)
    int* rowStart   = (int*)(pairs + N_EDGES);                   // 50001
    int* fill       = rowStart + (N_NODES + 1);                  // 50000 (hist counts)
    int* cursor     = fill + N_NODES;                            // 50000
    int* blockSums  = cursor + N_NODES;                          // 256

    const int scanBlocks = (N_NODES + 255) / 256;   // 196
    const int edgeBlocks = (N_EDGES + 255) / 256;   // 3125
    const int gemmBlocks = (N_NODES + 63) / 64;     // 782
    const int nodeBlocks = (N_NODES + 3) / 4;       // 12500

    // H1(bf16) = x @ W1
    gemm_kernel<128, 8><<<gemmBlocks, 256, 0, stream>>>(x, W1, (ushort16*)H1, N_NODES);

    // CSR by dst
    hipMemsetAsync(fill, 0, N_NODES * sizeof(int), stream);
    hist_kernel<<<edgeBlocks, 256, 0, stream>>>(ei, fill);
    scan1_kernel<<<scanBlocks, 256, 0, stream>>>(fill, rowStart, blockSums, N_NODES);
    scan2_kernel<<<1, 256, 0, stream>>>(blockSums, scanBlocks);
    scan3_kernel<<<scanBlocks, 256, 0, stream>>>(rowStart, blockSums, cursor, N_NODES);
    scatter_kernel<<<edgeBlocks, 256, 0, stream>>>(ei, ew, cursor, pairs);

    // A1 = relu(segment_sum(w * H1[src]) + b1)
    agg1_kernel<<<nodeBlocks, 256, 0, stream>>>(H1, rowStart, pairs, b1, A1);

    // H2(bf16) = A1 @ W2
    gemm_kernel<64, 4><<<gemmBlocks, 256, 0, stream>>>(A1, W2, H2, N_NODES);

    // out = segment_sum(H2[src]) + b2
    agg2_kernel<<<nodeBlocks, 256, 0, stream>>>(H2, rowStart, pairs, b2, out);
}

// Round 4
// 256.627 us; speedup vs baseline: 1.1618x; 1.1618x over previous
//
#include <hip/hip_runtime.h>

#define N_NODES 50000
#define N_EDGES 800000
#define IN_C    128
#define HID_C   128
#define OUT_C   64

typedef unsigned int   uint32;
typedef unsigned short ushort16;

__device__ __forceinline__ ushort16 f2bf(float f) {
    uint32 u = __float_as_uint(f);
    u += 0x7FFFu + ((u >> 16) & 1u);        // RNE
    return (ushort16)(u >> 16);
}
__device__ __forceinline__ float bf_lo(uint32 h) { return __uint_as_float(h << 16); }
__device__ __forceinline__ float bf_hi(uint32 h) { return __uint_as_float(h & 0xFFFF0000u); }

__device__ __forceinline__ ushort16 f2h_bits(float f) {
    union { _Float16 h; ushort16 u; } cv;
    cv.h = (_Float16)f;
    return cv.u;
}
__device__ __forceinline__ float h_bits2f(uint32 bits) {
    union { ushort16 u; _Float16 h; } cv;
    cv.u = (ushort16)bits;
    return (float)cv.h;
}

// ---------------- GEMM: C[M,N](bf16) = A[M,128](fp32) * W[128,N](fp32) -------
template<int N, int RPT>
__global__ __launch_bounds__(256) void gemm_kernel(const float* __restrict__ A,
                                                   const float* __restrict__ W,
                                                   ushort16* __restrict__ C, int M) {
    constexpr int BK   = 16;
    constexpr int COLT = N / 4;
    constexpr int BM   = (256 / COLT) * RPT;       // 64
    __shared__ float As[BK][BM + 4];
    __shared__ float Ws[BK][N];

    const int tid      = threadIdx.x;
    const int colLane  = tid % COLT;
    const int rowGroup = tid / COLT;
    const int blockRow = blockIdx.x * BM;

    float acc[RPT][4];
#pragma unroll
    for (int i = 0; i < RPT; i++)
#pragma unroll
        for (int j = 0; j < 4; j++) acc[i][j] = 0.f;

    for (int kk = 0; kk < 128; kk += BK) {
        {
            int r  = tid / 4;
            int k4 = (tid % 4) * 4;
            int gr = blockRow + r; if (gr > M - 1) gr = M - 1;
            float4 v = *((const float4*)&A[gr * 128 + kk + k4]);
            As[k4 + 0][r] = v.x; As[k4 + 1][r] = v.y;
            As[k4 + 2][r] = v.z; As[k4 + 3][r] = v.w;
        }
#pragma unroll
        for (int p = 0; p < (BK * N) / 1024; p++) {
            int l4 = tid + 256 * p;
            int k  = l4 / (N / 4), c4 = l4 % (N / 4);
            float4 v = *((const float4*)&W[(kk + k) * N + c4 * 4]);
            *((float4*)&Ws[k][c4 * 4]) = v;
        }
        __syncthreads();

#pragma unroll
        for (int k = 0; k < BK; k++) {
            float4 w = *((const float4*)&Ws[k][colLane * 4]);
            float a[RPT];
#pragma unroll
            for (int i = 0; i < RPT; i += 4) {
                float4 av = *((const float4*)&As[k][rowGroup * RPT + i]);
                a[i] = av.x; a[i + 1] = av.y; a[i + 2] = av.z; a[i + 3] = av.w;
            }
#pragma unroll
            for (int i = 0; i < RPT; i++) {
                acc[i][0] += a[i] * w.x; acc[i][1] += a[i] * w.y;
                acc[i][2] += a[i] * w.z; acc[i][3] += a[i] * w.w;
            }
        }
        __syncthreads();
    }

#pragma unroll
    for (int i = 0; i < RPT; i++) {
        int r = blockRow + rowGroup * RPT + i;
        if (r < M) {
            ushort4 pk;
            pk.x = f2bf(acc[i][0]); pk.y = f2bf(acc[i][1]);
            pk.z = f2bf(acc[i][2]); pk.w = f2bf(acc[i][3]);
            *((ushort4*)&C[r * N + colLane * 4]) = pk;
        }
    }
}

// ---------------- CSR build --------------------------------------------------
// histogram AND per-edge rank (the atomic's return value IS the segment rank)
__global__ void hist_kernel(const int* __restrict__ ei, int* __restrict__ counts,
                            ushort16* __restrict__ rank) {
    int e = blockIdx.x * 256 + threadIdx.x;
    if (e < N_EDGES) {
        int r = atomicAdd(&counts[ei[N_EDGES + e]], 1);
        rank[e] = (ushort16)r;
    }
}

__global__ void scan1_kernel(const int* __restrict__ counts, int* __restrict__ rowStart,
                             int* __restrict__ blockSums, int n) {
    __shared__ int lds[256];
    int t = threadIdx.x, g = blockIdx.x * 256 + t;
    int v = (g < n) ? counts[g] : 0;
    lds[t] = v; __syncthreads();
#pragma unroll
    for (int off = 1; off < 256; off <<= 1) {
        int a = (t >= off) ? lds[t - off] : 0;
        __syncthreads();
        lds[t] += a;
        __syncthreads();
    }
    if (g < n) rowStart[g] = lds[t] - v;
    if (t == 255) blockSums[blockIdx.x] = lds[255];
}

__global__ void scan2_kernel(int* __restrict__ blockSums, int nb) {
    __shared__ int lds[256];
    int t = threadIdx.x;
    int v = (t < nb) ? blockSums[t] : 0;
    lds[t] = v; __syncthreads();
#pragma unroll
    for (int off = 1; off < 256; off <<= 1) {
        int a = (t >= off) ? lds[t - off] : 0;
        __syncthreads();
        lds[t] += a;
        __syncthreads();
    }
    if (t < nb) blockSums[t] = lds[t] - v;
}

__global__ void scan3_kernel(int* __restrict__ rowStart, const int* __restrict__ blockSums, int n) {
    int g = blockIdx.x * 256 + threadIdx.x;
    if (g < n) rowStart[g] += blockSums[blockIdx.x];
    if (g == 0) rowStart[n] = N_EDGES;
}

// atomic-free scatter: pos = rowStart[dst] + rank[e]
__global__ void scatter_kernel(const int* __restrict__ ei, const float* __restrict__ ew,
                               const int* __restrict__ rowStart,
                               const ushort16* __restrict__ rank,
                               uint32* __restrict__ pairs) {
    int e = blockIdx.x * 256 + threadIdx.x;
    if (e < N_EDGES) {
        int dst = ei[N_EDGES + e];
        uint32 pk = (uint32)(ei[e]) | ((uint32)f2h_bits(ew[e]) << 16);
        int pos = rowStart[dst] + (int)rank[e];
        pairs[pos] = pk;
    }
}

// ---------------- Aggregations ----------------------------------------------
// layer 1: A1[i] = relu(b1 + sum_e w_e * H1[src_e]); H1 bf16x2 per lane (128 ch)
__global__ __launch_bounds__(256) void agg1_kernel(const uint32* __restrict__ H1,
                                                   const int* __restrict__ rowStart,
                                                   const uint32* __restrict__ pairs,
                                                   const float* __restrict__ b1,
                                                   float* __restrict__ A1) {
    int node = blockIdx.x * 4 + (threadIdx.x >> 6);
    int lane = threadIdx.x & 63;
    if (node >= N_NODES) return;
    int s = rowStart[node], e = rowStart[node + 1];
    float2 acc = ((const float2*)b1)[lane];
    int i = s;
    for (; i + 8 <= e; i += 8) {
        uint32 p[8], h[8];
#pragma unroll
        for (int j = 0; j < 8; j++) p[j] = pairs[i + j];
#pragma unroll
        for (int j = 0; j < 8; j++) h[j] = H1[(p[j] & 0xFFFFu) * 64 + lane];
#pragma unroll
        for (int j = 0; j < 8; j++) {
            float w = h_bits2f(p[j] >> 16);
            acc.x += w * bf_lo(h[j]);
            acc.y += w * bf_hi(h[j]);
        }
    }
    for (; i < e; i++) {
        uint32 p = pairs[i];
        uint32 h = H1[(p & 0xFFFFu) * 64 + lane];
        float  w = h_bits2f(p >> 16);
        acc.x += w * bf_lo(h);
        acc.y += w * bf_hi(h);
    }
    float2 r; r.x = fmaxf(acc.x, 0.f); r.y = fmaxf(acc.y, 0.f);
    ((float2*)A1)[node * 64 + lane] = r;
}

// layer 2: out[i] = b2 + sum_e H2[src_e]; H2 bf16 per lane (64 ch)
__global__ __launch_bounds__(256) void agg2_kernel(const ushort16* __restrict__ H2,
                                                   const int* __restrict__ rowStart,
                                                   const uint32* __restrict__ pairs,
                                                   const float* __restrict__ b2,
                                                   float* __restrict__ out) {
    int node = blockIdx.x * 4 + (threadIdx.x >> 6);
    int lane = threadIdx.x & 63;
    if (node >= N_NODES) return;
    int s = rowStart[node], e = rowStart[node + 1];
    float acc = b2[lane];
    int i = s;
    for (; i + 8 <= e; i += 8) {
        uint32 v[8];
#pragma unroll
        for (int j = 0; j < 8; j++) v[j] = H2[(pairs[i + j] & 0xFFFFu) * 64 + lane];
#pragma unroll
        for (int j = 0; j < 8; j++) acc += __uint_as_float(v[j] << 16);
    }
    for (; i < e; i++) {
        uint32 v = H2[(pairs[i] & 0xFFFFu) * 64 + lane];
        acc += __uint_as_float(v << 16);
    }
    out[node * 64 + lane] = acc;
}

// ---------------- launch -----------------------------------------------------
extern "C" void kernel_launch(void* const* d_in, const int* in_sizes, int n_in,
                              void* d_out, int out_size, void* d_ws, size_t ws_size,
                              hipStream_t stream) {
    const float* x  = (const float*)d_in[0];
    const int*   ei = (const int*)  d_in[1];   // [2, E] int32
    const float* ew = (const float*)d_in[2];
    const float* W1 = (const float*)d_in[3];
    const float* b1 = (const float*)d_in[4];
    const float* W2 = (const float*)d_in[5];
    const float* b2 = (const float*)d_in[6];
    float* out = (float*)d_out;

    // workspace layout
    float*    A1    = (float*)d_ws;                              // 50000*128 f32
    uint32*   H1    = (uint32*)(A1 + (size_t)N_NODES * HID_C);   // 50000*64 u32 (bf16x2)
    ushort16* H2    = (ushort16*)(H1 + (size_t)N_NODES * 64);    // 50000*64 bf16
    uint32*   pairs = (uint32*)(H2 + (size_t)N_NODES * OUT_C);   // 800000 (src u16 | f16 w)
    ushort16* rank  = (ushort16*)(pairs + N_EDGES);              // 800000 u16
    int* rowStart   = (int*)(rank + N_EDGES);                    // 50001
    int* counts     = rowStart + (N_NODES + 1);                  // 50000
    int* blockSums  = counts + N_NODES;                          // 256

    const int scanBlocks = (N_NODES + 255) / 256;   // 196
    const int edgeBlocks = (N_EDGES + 255) / 256;   // 3125
    const int gemmBlocks = (N_NODES + 63) / 64;     // 782
    const int nodeBlocks = (N_NODES + 3) / 4;       // 12500

    // H1(bf16) = x @ W1
    gemm_kernel<128, 8><<<gemmBlocks, 256, 0, stream>>>(x, W1, (ushort16*)H1, N_NODES);

    // CSR by dst (hist also emits per-edge segment rank -> scatter is atomic-free)
    hipMemsetAsync(counts, 0, N_NODES * sizeof(int), stream);
    hist_kernel<<<edgeBlocks, 256, 0, stream>>>(ei, counts, rank);
    scan1_kernel<<<scanBlocks, 256, 0, stream>>>(counts, rowStart, blockSums, N_NODES);
    scan2_kernel<<<1, 256, 0, stream>>>(blockSums, scanBlocks);
    scan3_kernel<<<scanBlocks, 256, 0, stream>>>(rowStart, blockSums, N_NODES);
    scatter_kernel<<<edgeBlocks, 256, 0, stream>>>(ei, ew, rowStart, rank, pairs);

    // A1 = relu(segment_sum(w * H1[src]) + b1)
    agg1_kernel<<<nodeBlocks, 256, 0, stream>>>(H1, rowStart, pairs, b1, A1);

    // H2(bf16) = A1 @ W2
    gemm_kernel<64, 4><<<gemmBlocks, 256, 0, stream>>>(A1, W2, H2, N_NODES);

    // out = segment_sum(H2[src]) + b2
    agg2_kernel<<<nodeBlocks, 256, 0, stream>>>(H2, rowStart, pairs, b2, out);
}